// Round 4
// baseline (777.444 us; speedup 1.0000x reference)
//
#include <hip/hip_runtime.h>
#include <math.h>
#include <float.h>

#define BGRAPH 16
#define NPTS   2048
#define CDIM   16
#define ODIM   64
#define KNN    16
#define NTOT   (BGRAPH*NPTS)     // 32768
#define NEDGE  (NTOT*KNN)        // 524288
#define EPSBN  1e-5f
#define NBLK_E 2048              // blocks for edge-stat passes
#define NPW    4                 // nodes per wave in edge-stat passes

// ---------------- P = x@W1b, Q = x@(W1a-W1b)+b1, sq = rowsum(x*x) ----------
__global__ __launch_bounds__(256) void pq_kernel(
    const float* __restrict__ x, const float* __restrict__ W1,
    const float* __restrict__ b1,
    float* __restrict__ P, float* __restrict__ Q, float* __restrict__ sq) {
  int lane = threadIdx.x & 63;
  int nin  = threadIdx.x >> 6;           // node within block (0..3)
  int node = blockIdx.x * 4 + nin;
  __shared__ float xs[4][CDIM];
  if (threadIdx.x < 4*CDIM) {
    int n = threadIdx.x / CDIM, c = threadIdx.x % CDIM;
    xs[n][c] = x[(blockIdx.x*4 + n)*CDIM + c];
  }
  __syncthreads();
  float p = 0.f, q = b1[lane];
  #pragma unroll
  for (int c = 0; c < CDIM; ++c) {
    float xv = xs[nin][c];
    float wb = W1[(c+CDIM)*ODIM + lane];
    float wa = W1[c*ODIM + lane];
    p += xv * wb;
    q += xv * (wa - wb);
  }
  P[node*ODIM + lane] = p;
  Q[node*ODIM + lane] = q;
  if (lane == 0) {
    float s = 0.f;
    #pragma unroll
    for (int c = 0; c < CDIM; ++c) { float xv = xs[nin][c]; s += xv*xv; }
    sq[node] = s;
  }
}

// ---------------- kNN: wave-local selection, registers fully static ---------
#define KROWS 8
__device__ __forceinline__ unsigned long long packkey(float dv, int j) {
  unsigned ub = __float_as_uint(dv);
  ub ^= ((unsigned)((int)ub >> 31)) | 0x80000000u;   // monotone f32->u32
  return (((unsigned long long)ub) << 32) | (unsigned)j;
}

__global__ __launch_bounds__(256) void knn_kernel(
    const float* __restrict__ x, const float* __restrict__ sq,
    int* __restrict__ idxOut) {
  __shared__ float sT16[CDIM][256];                 // transposed tile, 16 KB
  __shared__ unsigned long long skey[4][64];        // per-wave survivor keys
  __shared__ int scnt[4];
  const int tid  = threadIdx.x;
  const int lane = tid & 63;
  const int w    = tid >> 6;
  const int blocksPerGraph = NPTS / KROWS;          // 256
  const int g     = blockIdx.x / blocksPerGraph;
  const int rb    = (blockIdx.x % blocksPerGraph) * KROWS;
  const int gbase = g * NPTS;
  const int r0    = rb + w*2;                       // this wave's rows: r0, r0+1

  float tg[2][CDIM]; float tsq[2];
  #pragma unroll
  for (int rp = 0; rp < 2; ++rp) {
    const float4* tp = (const float4*)(x + (size_t)(gbase + r0 + rp)*CDIM);
    float4 t0 = tp[0], t1 = tp[1], t2 = tp[2], t3 = tp[3];
    tg[rp][0]=t0.x; tg[rp][1]=t0.y; tg[rp][2]=t0.z; tg[rp][3]=t0.w;
    tg[rp][4]=t1.x; tg[rp][5]=t1.y; tg[rp][6]=t1.z; tg[rp][7]=t1.w;
    tg[rp][8]=t2.x; tg[rp][9]=t2.y; tg[rp][10]=t2.z; tg[rp][11]=t2.w;
    tg[rp][12]=t3.x; tg[rp][13]=t3.y; tg[rp][14]=t3.z; tg[rp][15]=t3.w;
    tsq[rp] = sq[gbase + r0 + rp];
  }

  float d[2][32];   // MUST stay in VGPRs: all indexing below is fully unrolled

  #pragma unroll
  for (int t = 0; t < NPTS/256; ++t) {
    __syncthreads();
    const float4* xp = (const float4*)(x + (size_t)(gbase + t*256 + tid)*CDIM);
    float4 a0 = xp[0], a1 = xp[1], a2 = xp[2], a3 = xp[3];
    sT16[0][tid]=a0.x;  sT16[1][tid]=a0.y;  sT16[2][tid]=a0.z;  sT16[3][tid]=a0.w;
    sT16[4][tid]=a1.x;  sT16[5][tid]=a1.y;  sT16[6][tid]=a1.z;  sT16[7][tid]=a1.w;
    sT16[8][tid]=a2.x;  sT16[9][tid]=a2.y;  sT16[10][tid]=a2.z; sT16[11][tid]=a2.w;
    sT16[12][tid]=a3.x; sT16[13][tid]=a3.y; sT16[14][tid]=a3.z; sT16[15][tid]=a3.w;
    __syncthreads();

    float4 sq4 = *(const float4*)(sq + gbase + t*256 + 4*lane);
    float sqv[4] = {sq4.x, sq4.y, sq4.z, sq4.w};

    float dot[2][4] = {{0.f,0.f,0.f,0.f},{0.f,0.f,0.f,0.f}};
    #pragma unroll
    for (int c = 0; c < CDIM; ++c) {
      float4 cv = *(const float4*)(&sT16[c][4*lane]);
      float cvv[4]; cvv[0]=cv.x; cvv[1]=cv.y; cvv[2]=cv.z; cvv[3]=cv.w;
      #pragma unroll
      for (int rp = 0; rp < 2; ++rp)
        #pragma unroll
        for (int rr = 0; rr < 4; ++rr)
          dot[rp][rr] += tg[rp][c] * cvv[rr];
    }
    #pragma unroll
    for (int rp = 0; rp < 2; ++rp)
      #pragma unroll
      for (int rr = 0; rr < 4; ++rr)
        d[rp][t*4 + rr] = tsq[rp] + sqv[rr] - 2.f*dot[rp][rr];
  }

  #pragma unroll
  for (int rp = 0; rp < 2; ++rp) {
    float lmin = d[rp][0];
    #pragma unroll
    for (int s = 1; s < 32; ++s) lmin = fminf(lmin, d[rp][s]);

    float v = lmin;
    #pragma unroll
    for (int k = 2; k <= 64; k <<= 1) {
      #pragma unroll
      for (int j = k >> 1; j > 0; j >>= 1) {
        float o = __shfl_xor(v, j);
        bool asc   = ((lane & k) == 0);
        bool lower = ((lane & j) == 0);
        float mn = fminf(v, o), mx = fmaxf(v, o);
        v = (asc == lower) ? mn : mx;
      }
    }
    float T = __shfl(v, 15);

    if (lane == 0) scnt[w] = 0;
    #pragma unroll
    for (int s = 0; s < 32; ++s) {
      if (d[rp][s] <= T) {
        int p = atomicAdd(&scnt[w], 1);
        if (p < 64) {
          int j = (s >> 2)*256 + 4*lane + (s & 3);
          skey[w][p] = packkey(d[rp][s], j);
        }
      }
    }
    int M = scnt[w];
    int row = gbase + r0 + rp;

    if (M <= 64) {
      unsigned long long key = (lane < M) ? skey[w][lane] : ~0ull;
      #pragma unroll
      for (int k = 2; k <= 64; k <<= 1) {
        #pragma unroll
        for (int j = k >> 1; j > 0; j >>= 1) {
          unsigned long long o = __shfl_xor(key, j);
          bool asc   = ((lane & k) == 0);
          bool lower = ((lane & j) == 0);
          unsigned long long mn = (key < o) ? key : o;
          unsigned long long mx = (key < o) ? o : key;
          key = (asc == lower) ? mn : mx;
        }
      }
      if (lane < KNN)
        idxOut[(size_t)row*KNN + lane] = gbase + (int)(key & 0xffffffffu);
    } else {
      for (int sel = 0; sel < KNN; ++sel) {
        unsigned long long lb = ~0ull;
        #pragma unroll
        for (int s = 0; s < 32; ++s) {
          int j = (s >> 2)*256 + 4*lane + (s & 3);
          unsigned long long ks = packkey(d[rp][s], j);
          if (ks < lb) lb = ks;
        }
        #pragma unroll
        for (int off = 32; off > 0; off >>= 1) {
          unsigned long long o = __shfl_xor(lb, off);
          if (o < lb) lb = o;
        }
        if (lane == 0)
          idxOut[(size_t)row*KNN + sel] = gbase + (int)(lb & 0xffffffffu);
        #pragma unroll
        for (int s = 0; s < 32; ++s) {
          int j = (s >> 2)*256 + 4*lane + (s & 3);
          if (packkey(d[rp][s], j) == lb) d[rp][s] = FLT_MAX;
        }
      }
    }
  }
}

// ---------------- stats pass 1: per-channel sum/sumsq of h ------------------
__global__ __launch_bounds__(256) void stats1_kernel(
    const float* __restrict__ P, const float* __restrict__ Q,
    const int* __restrict__ idx, float* __restrict__ pbuf) {
  int lane = threadIdx.x & 63;
  int wid  = threadIdx.x >> 6;
  int gw   = blockIdx.x * 4 + wid;
  int n0 = gw * NPW;
  float s = 0.f, ss = 0.f;
  #pragma unroll
  for (int ii = 0; ii < NPW; ++ii) {
    int i = n0 + ii;
    float qv = Q[(size_t)i*ODIM + lane];
    #pragma unroll
    for (int k = 0; k < KNN; ++k) {
      int j = idx[(size_t)i*KNN + k];
      float h = qv + P[(size_t)j*ODIM + lane];
      s += h; ss += h*h;
    }
  }
  __shared__ float ls[4][ODIM], lss[4][ODIM];
  ls[wid][lane] = s; lss[wid][lane] = ss;
  __syncthreads();
  int tid = threadIdx.x;
  if (tid < ODIM) {
    float a = ls[0][tid] + ls[1][tid] + ls[2][tid] + ls[3][tid];
    pbuf[(size_t)tid*NBLK_E + blockIdx.x] = a;
  } else if (tid < 2*ODIM) {
    int o = tid - ODIM;
    float a = lss[0][o] + lss[1][o] + lss[2][o] + lss[3][o];
    pbuf[(size_t)(ODIM+o)*NBLK_E + blockIdx.x] = a;
  }
}

__global__ __launch_bounds__(64) void fin1_kernel(
    const float* __restrict__ pbuf,
    const float* __restrict__ g1, const float* __restrict__ be1,
    float* __restrict__ scale, float* __restrict__ shift) {
  int o = blockIdx.x, lane = threadIdx.x;
  const float* ps = pbuf + (size_t)o*NBLK_E;
  const float* pq = pbuf + (size_t)(ODIM+o)*NBLK_E;
  float s = 0.f, ss = 0.f;
  for (int t = lane; t < NBLK_E; t += 64) { s += ps[t]; ss += pq[t]; }
  #pragma unroll
  for (int off = 32; off > 0; off >>= 1) {
    s  += __shfl_xor(s, off);
    ss += __shfl_xor(ss, off);
  }
  if (lane == 0) {
    float mu  = s / (float)NEDGE;
    float var = ss / (float)NEDGE - mu*mu;
    float inv = 1.0f / sqrtf(var + EPSBN);
    float sc = g1[o] * inv;
    scale[o] = sc;
    shift[o] = be1[o] - mu * sc;
  }
}

// ---------------- stats pass 2: gate values + scalar sum/sumsq --------------
__global__ __launch_bounds__(256) void stats2_kernel(
    const float* __restrict__ P, const float* __restrict__ Q,
    const int* __restrict__ idx, const float* __restrict__ scale,
    const float* __restrict__ shift, const float* __restrict__ Wg,
    const float* __restrict__ bg, float* __restrict__ gtbuf,
    float* __restrict__ gpart) {
  int lane = threadIdx.x & 63;
  int wid  = threadIdx.x >> 6;
  int gw   = blockIdx.x * 4 + wid;
  int n0 = gw * NPW;
  float sc = scale[lane], sh = shift[lane], wg = Wg[lane], bgv = bg[0];
  float s = 0.f, ss = 0.f;
  #pragma unroll
  for (int ii = 0; ii < NPW; ++ii) {
    int i = n0 + ii;
    float qv = Q[(size_t)i*ODIM + lane];
    #pragma unroll
    for (int k = 0; k < KNN; ++k) {
      int j = idx[(size_t)i*KNN + k];
      float z = (qv + P[(size_t)j*ODIM + lane]) * sc + sh;
      float hn = z / (1.f + expf(-z));
      float v = hn * wg;
      #pragma unroll
      for (int off = 32; off > 0; off >>= 1) v += __shfl_xor(v, off);
      float g = v + bgv;
      if (lane == 0) {
        gtbuf[(size_t)i*KNN + k] = g;
        s += g; ss += g*g;
      }
    }
  }
  __shared__ float pw[4], pws[4];
  if (lane == 0) { pw[wid] = s; pws[wid] = ss; }
  __syncthreads();
  if (threadIdx.x == 0) {
    gpart[2*blockIdx.x]   = pw[0]+pw[1]+pw[2]+pw[3];
    gpart[2*blockIdx.x+1] = pws[0]+pws[1]+pws[2]+pws[3];
  }
}

__global__ __launch_bounds__(256) void fin2_kernel(
    const float* __restrict__ gpart,
    const float* __restrict__ gg, const float* __restrict__ beg,
    float* __restrict__ gsc) {
  int tid = threadIdx.x;
  float s = 0.f, ss = 0.f;
  for (int t = tid; t < NBLK_E; t += 256) { s += gpart[2*t]; ss += gpart[2*t+1]; }
  __shared__ float as[256], bs[256];
  as[tid] = s; bs[tid] = ss;
  __syncthreads();
  #pragma unroll
  for (int st = 128; st > 0; st >>= 1) {
    if (tid < st) { as[tid] += as[tid+st]; bs[tid] += bs[tid+st]; }
    __syncthreads();
  }
  if (tid == 0) {
    float mu  = as[0] / (float)NEDGE;
    float var = bs[0] / (float)NEDGE - mu*mu;
    float inv = 1.f / sqrtf(var + EPSBN);
    float sg = gg[0] * inv;
    gsc[0] = sg; gsc[1] = beg[0] - mu * sg;
  }
}

// ---------------- final: hn, gate from gtbuf, softmax over K, weighted sum --
__global__ __launch_bounds__(256) void final_kernel(
    const float* __restrict__ P, const float* __restrict__ Q,
    const int* __restrict__ idx, const float* __restrict__ scale,
    const float* __restrict__ shift, const float* __restrict__ gtbuf,
    const float* __restrict__ gsc, float* __restrict__ out) {
  int lane = threadIdx.x & 63;
  int wid  = threadIdx.x >> 6;
  int i = blockIdx.x * 4 + wid;
  float sc = scale[lane], sh = shift[lane];
  float gscale = gsc[0], gshift = gsc[1];
  float qv = Q[(size_t)i*ODIM + lane];
  float hn[KNN], gt[KNN];
  #pragma unroll
  for (int k = 0; k < KNN; ++k) {
    int j = idx[(size_t)i*KNN + k];
    float z = (qv + P[(size_t)j*ODIM + lane]) * sc + sh;
    hn[k] = z / (1.f + expf(-z));
    float g = gtbuf[(size_t)i*KNN + k];
    float zg = g * gscale + gshift;
    gt[k] = zg / (1.f + expf(-zg));
  }
  float m = gt[0];
  #pragma unroll
  for (int k = 1; k < KNN; ++k) m = fmaxf(m, gt[k]);
  float se = 0.f;
  #pragma unroll
  for (int k = 0; k < KNN; ++k) { gt[k] = expf(gt[k] - m); se += gt[k]; }
  float invs = 1.f / se;
  float acc = 0.f;
  #pragma unroll
  for (int k = 0; k < KNN; ++k) acc += gt[k] * invs * hn[k];
  out[(size_t)i*ODIM + lane] = acc;
}

extern "C" void kernel_launch(void* const* d_in, const int* in_sizes, int n_in,
                              void* d_out, int out_size, void* d_ws, size_t ws_size,
                              hipStream_t stream) {
  const float* x   = (const float*)d_in[0];
  // d_in[1] = batch (unused: sorted equal-size graphs)
  const float* W1  = (const float*)d_in[2];
  const float* b1  = (const float*)d_in[3];
  const float* g1  = (const float*)d_in[4];
  const float* be1 = (const float*)d_in[5];
  const float* Wg  = (const float*)d_in[6];
  const float* bg  = (const float*)d_in[7];
  const float* gg  = (const float*)d_in[8];
  const float* beg = (const float*)d_in[9];
  float* out = (float*)d_out;

  char* ws = (char*)d_ws;
  int*   idx   = (int*)  (ws);                         // 2 MB
  float* P     = (float*)(ws + 2097152);               // 8 MB
  float* Q     = (float*)(ws + 10485760);              // 8 MB
  float* sq    = (float*)(ws + 18874368);              // 128 KB
  float* pbuf  = (float*)(ws + 19005440);              // 1 MB   [128][2048]
  float* gpart = (float*)(ws + 20054016);              // 16 KB  [2048][2]
  float* gtbuf = (float*)(ws + 20070400);              // 2 MB   [NEDGE]
  float* scale = (float*)(ws + 22167552);              // 64 f
  float* shift = (float*)(ws + 22167808);              // 64 f
  float* gsc   = (float*)(ws + 22168064);              // 2 f

  pq_kernel<<<NTOT/4, 256, 0, stream>>>(x, W1, b1, P, Q, sq);
  knn_kernel<<<NTOT/KROWS, 256, 0, stream>>>(x, sq, idx);
  stats1_kernel<<<NBLK_E, 256, 0, stream>>>(P, Q, idx, pbuf);
  fin1_kernel<<<ODIM, 64, 0, stream>>>(pbuf, g1, be1, scale, shift);
  stats2_kernel<<<NBLK_E, 256, 0, stream>>>(P, Q, idx, scale, shift, Wg, bg, gtbuf, gpart);
  fin2_kernel<<<1, 256, 0, stream>>>(gpart, gg, beg, gsc);
  final_kernel<<<NTOT/4, 256, 0, stream>>>(P, Q, idx, scale, shift, gtbuf, gsc, out);
}

// Round 5
// 362.241 us; speedup vs baseline: 2.1462x; 2.1462x over previous
//
#include <hip/hip_runtime.h>
#include <math.h>
#include <float.h>

#define BGRAPH 16
#define NPTS   2048
#define CDIM   16
#define ODIM   64
#define KNN    16
#define NTOT   (BGRAPH*NPTS)     // 32768
#define NEDGE  (NTOT*KNN)        // 524288
#define EPSBN  1e-5f
#define NBLK_E 2048              // blocks for edge-stat passes
#define NPW    4                 // nodes per wave in edge-stat passes

// ---------------- P = x@W1b, Q = x@(W1a-W1b)+b1, sq = rowsum(x*x) ----------
__global__ __launch_bounds__(256) void pq_kernel(
    const float* __restrict__ x, const float* __restrict__ W1,
    const float* __restrict__ b1,
    float* __restrict__ P, float* __restrict__ Q, float* __restrict__ sq) {
  int lane = threadIdx.x & 63;
  int nin  = threadIdx.x >> 6;           // node within block (0..3)
  int node = blockIdx.x * 4 + nin;
  __shared__ float xs[4][CDIM];
  if (threadIdx.x < 4*CDIM) {
    int n = threadIdx.x / CDIM, c = threadIdx.x % CDIM;
    xs[n][c] = x[(blockIdx.x*4 + n)*CDIM + c];
  }
  __syncthreads();
  float p = 0.f, q = b1[lane];
  #pragma unroll
  for (int c = 0; c < CDIM; ++c) {
    float xv = xs[nin][c];
    float wb = W1[(c+CDIM)*ODIM + lane];
    float wa = W1[c*ODIM + lane];
    p += xv * wb;
    q += xv * (wa - wb);
  }
  P[node*ODIM + lane] = p;
  Q[node*ODIM + lane] = q;
  if (lane == 0) {
    float s = 0.f;
    #pragma unroll
    for (int c = 0; c < CDIM; ++c) { float xv = xs[nin][c]; s += xv*xv; }
    sq[node] = s;
  }
}

// ---------------- kNN: distances in LDS, wave-local selection ---------------
// block = 256 thr = 4 waves; 1 row per wave; KROWS=4 rows/block; 8192 blocks.
// dmat[w][j] lives in LDS (32 KB) -> no VGPR pressure, no scratch spill.
#define KROWS 4
__device__ __forceinline__ unsigned long long packkey(float dv, int j) {
  unsigned ub = __float_as_uint(dv);
  ub ^= ((unsigned)((int)ub >> 31)) | 0x80000000u;   // monotone f32->u32
  return (((unsigned long long)ub) << 32) | (unsigned)j;
}

__global__ __launch_bounds__(256) void knn_kernel(
    const float* __restrict__ x, const float* __restrict__ sq,
    int* __restrict__ idxOut) {
  __shared__ float sT16[CDIM][256];                 // transposed tile, 16 KB
  __shared__ float dmat[4][NPTS];                   // per-wave distance row, 32 KB
  __shared__ unsigned long long skey[4][64];        // per-wave survivor keys
  __shared__ int scnt[4];
  const int tid  = threadIdx.x;
  const int lane = tid & 63;
  const int w    = tid >> 6;
  const int blocksPerGraph = NPTS / KROWS;          // 512
  const int g     = blockIdx.x / blocksPerGraph;
  const int rb    = (blockIdx.x % blocksPerGraph) * KROWS;
  const int gbase = g * NPTS;
  const int r     = rb + w;                         // this wave's row

  // target row -> registers (wave-uniform values)
  float tg[CDIM]; float tsq;
  {
    const float4* tp = (const float4*)(x + (size_t)(gbase + r)*CDIM);
    float4 t0 = tp[0], t1 = tp[1], t2 = tp[2], t3 = tp[3];
    tg[0]=t0.x;  tg[1]=t0.y;  tg[2]=t0.z;  tg[3]=t0.w;
    tg[4]=t1.x;  tg[5]=t1.y;  tg[6]=t1.z;  tg[7]=t1.w;
    tg[8]=t2.x;  tg[9]=t2.y;  tg[10]=t2.z; tg[11]=t2.w;
    tg[12]=t3.x; tg[13]=t3.y; tg[14]=t3.z; tg[15]=t3.w;
    tsq = sq[gbase + r];
  }

  for (int t = 0; t < NPTS/256; ++t) {              // runtime loop: no reg blowup
    __syncthreads();
    const float4* xp = (const float4*)(x + (size_t)(gbase + t*256 + tid)*CDIM);
    float4 a0 = xp[0], a1 = xp[1], a2 = xp[2], a3 = xp[3];
    sT16[0][tid]=a0.x;  sT16[1][tid]=a0.y;  sT16[2][tid]=a0.z;  sT16[3][tid]=a0.w;
    sT16[4][tid]=a1.x;  sT16[5][tid]=a1.y;  sT16[6][tid]=a1.z;  sT16[7][tid]=a1.w;
    sT16[8][tid]=a2.x;  sT16[9][tid]=a2.y;  sT16[10][tid]=a2.z; sT16[11][tid]=a2.w;
    sT16[12][tid]=a3.x; sT16[13][tid]=a3.y; sT16[14][tid]=a3.z; sT16[15][tid]=a3.w;
    __syncthreads();

    float4 sq4 = *(const float4*)(sq + gbase + t*256 + 4*lane);
    float sqv[4] = {sq4.x, sq4.y, sq4.z, sq4.w};

    float dot[4] = {0.f,0.f,0.f,0.f};
    #pragma unroll
    for (int c = 0; c < CDIM; ++c) {
      float4 cv = *(const float4*)(&sT16[c][4*lane]);   // ds_read_b128
      dot[0] += tg[c] * cv.x;
      dot[1] += tg[c] * cv.y;
      dot[2] += tg[c] * cv.z;
      dot[3] += tg[c] * cv.w;
    }
    float4 d4;
    d4.x = tsq + sqv[0] - 2.f*dot[0];
    d4.y = tsq + sqv[1] - 2.f*dot[1];
    d4.z = tsq + sqv[2] - 2.f*dot[2];
    d4.w = tsq + sqv[3] - 2.f*dot[3];
    *(float4*)(&dmat[w][t*256 + 4*lane]) = d4;      // own-wave LDS, no race
  }
  // dmat[w] written and read only by wave w -> no barrier needed below.

  // 1) per-lane min over this lane's 32 values
  float lmin = FLT_MAX;
  #pragma unroll
  for (int s = 0; s < 8; ++s) {
    float4 dv = *(const float4*)(&dmat[w][s*256 + 4*lane]);
    lmin = fminf(lmin, fminf(fminf(dv.x, dv.y), fminf(dv.z, dv.w)));
  }

  // 2) bitonic sort 64 lane-minima (f32 asc); lane 15 bounds the 16th-smallest
  float v = lmin;
  #pragma unroll
  for (int k = 2; k <= 64; k <<= 1) {
    #pragma unroll
    for (int j = k >> 1; j > 0; j >>= 1) {
      float o = __shfl_xor(v, j);
      bool asc   = ((lane & k) == 0);
      bool lower = ((lane & j) == 0);
      float mn = fminf(v, o), mx = fmaxf(v, o);
      v = (asc == lower) ? mn : mx;
    }
  }
  float T = __shfl(v, 15);

  // 3) filter + compact survivors into per-wave LDS
  if (lane == 0) scnt[w] = 0;
  #pragma unroll
  for (int s = 0; s < 8; ++s) {
    float4 dv = *(const float4*)(&dmat[w][s*256 + 4*lane]);
    float dr[4] = {dv.x, dv.y, dv.z, dv.w};
    #pragma unroll
    for (int rr = 0; rr < 4; ++rr) {
      if (dr[rr] <= T) {
        int p = atomicAdd(&scnt[w], 1);
        if (p < 64) skey[w][p] = packkey(dr[rr], s*256 + 4*lane + rr);
      }
    }
  }
  int M = scnt[w];
  int row = gbase + r;

  if (M <= 64) {
    // 4) u64 bitonic sort across lanes; lanes 0..15 hold the top-16
    unsigned long long key = (lane < M) ? skey[w][lane] : ~0ull;
    #pragma unroll
    for (int k = 2; k <= 64; k <<= 1) {
      #pragma unroll
      for (int j = k >> 1; j > 0; j >>= 1) {
        unsigned long long o = __shfl_xor(key, j);
        bool asc   = ((lane & k) == 0);
        bool lower = ((lane & j) == 0);
        unsigned long long mn = (key < o) ? key : o;
        unsigned long long mx = (key < o) ? o : key;
        key = (asc == lower) ? mn : mx;
      }
    }
    if (lane < KNN)
      idxOut[(size_t)row*KNN + lane] = gbase + (int)(key & 0xffffffffu);
  } else {
    // exact fallback (astronomically rare): 16 argmin rounds over LDS
    for (int sel = 0; sel < KNN; ++sel) {
      unsigned long long lb = ~0ull;
      #pragma unroll
      for (int s = 0; s < 8; ++s) {
        float4 dv = *(const float4*)(&dmat[w][s*256 + 4*lane]);
        float dr[4] = {dv.x, dv.y, dv.z, dv.w};
        #pragma unroll
        for (int rr = 0; rr < 4; ++rr) {
          unsigned long long ks = packkey(dr[rr], s*256 + 4*lane + rr);
          if (ks < lb) lb = ks;
        }
      }
      #pragma unroll
      for (int off = 32; off > 0; off >>= 1) {
        unsigned long long o = __shfl_xor(lb, off);
        if (o < lb) lb = o;
      }
      if (lane == 0) {
        int jwin = (int)(lb & 0xffffffffu);
        idxOut[(size_t)row*KNN + sel] = gbase + jwin;
        dmat[w][jwin] = FLT_MAX;
      }
    }
  }
}

// ---------------- stats pass 1: per-channel sum/sumsq of h ------------------
__global__ __launch_bounds__(256) void stats1_kernel(
    const float* __restrict__ P, const float* __restrict__ Q,
    const int* __restrict__ idx, float* __restrict__ pbuf) {
  int lane = threadIdx.x & 63;
  int wid  = threadIdx.x >> 6;
  int gw   = blockIdx.x * 4 + wid;
  int n0 = gw * NPW;
  float s = 0.f, ss = 0.f;
  #pragma unroll
  for (int ii = 0; ii < NPW; ++ii) {
    int i = n0 + ii;
    float qv = Q[(size_t)i*ODIM + lane];
    #pragma unroll
    for (int k = 0; k < KNN; ++k) {
      int j = idx[(size_t)i*KNN + k];
      float h = qv + P[(size_t)j*ODIM + lane];
      s += h; ss += h*h;
    }
  }
  __shared__ float ls[4][ODIM], lss[4][ODIM];
  ls[wid][lane] = s; lss[wid][lane] = ss;
  __syncthreads();
  int tid = threadIdx.x;
  if (tid < ODIM) {
    float a = ls[0][tid] + ls[1][tid] + ls[2][tid] + ls[3][tid];
    pbuf[(size_t)tid*NBLK_E + blockIdx.x] = a;
  } else if (tid < 2*ODIM) {
    int o = tid - ODIM;
    float a = lss[0][o] + lss[1][o] + lss[2][o] + lss[3][o];
    pbuf[(size_t)(ODIM+o)*NBLK_E + blockIdx.x] = a;
  }
}

__global__ __launch_bounds__(64) void fin1_kernel(
    const float* __restrict__ pbuf,
    const float* __restrict__ g1, const float* __restrict__ be1,
    float* __restrict__ scale, float* __restrict__ shift) {
  int o = blockIdx.x, lane = threadIdx.x;
  const float* ps = pbuf + (size_t)o*NBLK_E;
  const float* pq = pbuf + (size_t)(ODIM+o)*NBLK_E;
  float s = 0.f, ss = 0.f;
  for (int t = lane; t < NBLK_E; t += 64) { s += ps[t]; ss += pq[t]; }
  #pragma unroll
  for (int off = 32; off > 0; off >>= 1) {
    s  += __shfl_xor(s, off);
    ss += __shfl_xor(ss, off);
  }
  if (lane == 0) {
    float mu  = s / (float)NEDGE;
    float var = ss / (float)NEDGE - mu*mu;
    float inv = 1.0f / sqrtf(var + EPSBN);
    float sc = g1[o] * inv;
    scale[o] = sc;
    shift[o] = be1[o] - mu * sc;
  }
}

// ---------------- stats pass 2: gate values + scalar sum/sumsq --------------
__global__ __launch_bounds__(256) void stats2_kernel(
    const float* __restrict__ P, const float* __restrict__ Q,
    const int* __restrict__ idx, const float* __restrict__ scale,
    const float* __restrict__ shift, const float* __restrict__ Wg,
    const float* __restrict__ bg, float* __restrict__ gtbuf,
    float* __restrict__ gpart) {
  int lane = threadIdx.x & 63;
  int wid  = threadIdx.x >> 6;
  int gw   = blockIdx.x * 4 + wid;
  int n0 = gw * NPW;
  float sc = scale[lane], sh = shift[lane], wg = Wg[lane], bgv = bg[0];
  float s = 0.f, ss = 0.f;
  #pragma unroll
  for (int ii = 0; ii < NPW; ++ii) {
    int i = n0 + ii;
    float qv = Q[(size_t)i*ODIM + lane];
    #pragma unroll
    for (int k = 0; k < KNN; ++k) {
      int j = idx[(size_t)i*KNN + k];
      float z = (qv + P[(size_t)j*ODIM + lane]) * sc + sh;
      float hn = z / (1.f + expf(-z));
      float v = hn * wg;
      #pragma unroll
      for (int off = 32; off > 0; off >>= 1) v += __shfl_xor(v, off);
      float g = v + bgv;
      if (lane == 0) {
        gtbuf[(size_t)i*KNN + k] = g;
        s += g; ss += g*g;
      }
    }
  }
  __shared__ float pw[4], pws[4];
  if (lane == 0) { pw[wid] = s; pws[wid] = ss; }
  __syncthreads();
  if (threadIdx.x == 0) {
    gpart[2*blockIdx.x]   = pw[0]+pw[1]+pw[2]+pw[3];
    gpart[2*blockIdx.x+1] = pws[0]+pws[1]+pws[2]+pws[3];
  }
}

__global__ __launch_bounds__(256) void fin2_kernel(
    const float* __restrict__ gpart,
    const float* __restrict__ gg, const float* __restrict__ beg,
    float* __restrict__ gsc) {
  int tid = threadIdx.x;
  float s = 0.f, ss = 0.f;
  for (int t = tid; t < NBLK_E; t += 256) { s += gpart[2*t]; ss += gpart[2*t+1]; }
  __shared__ float as[256], bs[256];
  as[tid] = s; bs[tid] = ss;
  __syncthreads();
  #pragma unroll
  for (int st = 128; st > 0; st >>= 1) {
    if (tid < st) { as[tid] += as[tid+st]; bs[tid] += bs[tid+st]; }
    __syncthreads();
  }
  if (tid == 0) {
    float mu  = as[0] / (float)NEDGE;
    float var = bs[0] / (float)NEDGE - mu*mu;
    float inv = 1.f / sqrtf(var + EPSBN);
    float sg = gg[0] * inv;
    gsc[0] = sg; gsc[1] = beg[0] - mu * sg;
  }
}

// ---------------- final: hn, gate from gtbuf, softmax over K, weighted sum --
__global__ __launch_bounds__(256) void final_kernel(
    const float* __restrict__ P, const float* __restrict__ Q,
    const int* __restrict__ idx, const float* __restrict__ scale,
    const float* __restrict__ shift, const float* __restrict__ gtbuf,
    const float* __restrict__ gsc, float* __restrict__ out) {
  int lane = threadIdx.x & 63;
  int wid  = threadIdx.x >> 6;
  int i = blockIdx.x * 4 + wid;
  float sc = scale[lane], sh = shift[lane];
  float gscale = gsc[0], gshift = gsc[1];
  float qv = Q[(size_t)i*ODIM + lane];
  float hn[KNN], gt[KNN];
  #pragma unroll
  for (int k = 0; k < KNN; ++k) {
    int j = idx[(size_t)i*KNN + k];
    float z = (qv + P[(size_t)j*ODIM + lane]) * sc + sh;
    hn[k] = z / (1.f + expf(-z));
    float g = gtbuf[(size_t)i*KNN + k];
    float zg = g * gscale + gshift;
    gt[k] = zg / (1.f + expf(-zg));
  }
  float m = gt[0];
  #pragma unroll
  for (int k = 1; k < KNN; ++k) m = fmaxf(m, gt[k]);
  float se = 0.f;
  #pragma unroll
  for (int k = 0; k < KNN; ++k) { gt[k] = expf(gt[k] - m); se += gt[k]; }
  float invs = 1.f / se;
  float acc = 0.f;
  #pragma unroll
  for (int k = 0; k < KNN; ++k) acc += gt[k] * invs * hn[k];
  out[(size_t)i*ODIM + lane] = acc;
}

extern "C" void kernel_launch(void* const* d_in, const int* in_sizes, int n_in,
                              void* d_out, int out_size, void* d_ws, size_t ws_size,
                              hipStream_t stream) {
  const float* x   = (const float*)d_in[0];
  // d_in[1] = batch (unused: sorted equal-size graphs)
  const float* W1  = (const float*)d_in[2];
  const float* b1  = (const float*)d_in[3];
  const float* g1  = (const float*)d_in[4];
  const float* be1 = (const float*)d_in[5];
  const float* Wg  = (const float*)d_in[6];
  const float* bg  = (const float*)d_in[7];
  const float* gg  = (const float*)d_in[8];
  const float* beg = (const float*)d_in[9];
  float* out = (float*)d_out;

  char* ws = (char*)d_ws;
  int*   idx   = (int*)  (ws);                         // 2 MB
  float* P     = (float*)(ws + 2097152);               // 8 MB
  float* Q     = (float*)(ws + 10485760);              // 8 MB
  float* sq    = (float*)(ws + 18874368);              // 128 KB
  float* pbuf  = (float*)(ws + 19005440);              // 1 MB   [128][2048]
  float* gpart = (float*)(ws + 20054016);              // 16 KB  [2048][2]
  float* gtbuf = (float*)(ws + 20070400);              // 2 MB   [NEDGE]
  float* scale = (float*)(ws + 22167552);              // 64 f
  float* shift = (float*)(ws + 22167808);              // 64 f
  float* gsc   = (float*)(ws + 22168064);              // 2 f

  pq_kernel<<<NTOT/4, 256, 0, stream>>>(x, W1, b1, P, Q, sq);
  knn_kernel<<<NTOT/KROWS, 256, 0, stream>>>(x, sq, idx);
  stats1_kernel<<<NBLK_E, 256, 0, stream>>>(P, Q, idx, pbuf);
  fin1_kernel<<<ODIM, 64, 0, stream>>>(pbuf, g1, be1, scale, shift);
  stats2_kernel<<<NBLK_E, 256, 0, stream>>>(P, Q, idx, scale, shift, Wg, bg, gtbuf, gpart);
  fin2_kernel<<<1, 256, 0, stream>>>(gpart, gg, beg, gsc);
  final_kernel<<<NTOT/4, 256, 0, stream>>>(P, Q, idx, scale, shift, gtbuf, gsc, out);
}